// Round 5
// baseline (818.963 us; speedup 1.0000x reference)
//
#include <hip/hip_runtime.h>
#include <hip/hip_bf16.h>
#include <math.h>

// Problem constants (fixed by reference)
#define BATCH 2
#define SEQ   2048
#define DMODEL 2048
#define NHEADS 16
#define HDIM  128
#define MROWS (BATCH * SEQ)   // 4096

typedef __attribute__((ext_vector_type(8))) short short8;
typedef __attribute__((ext_vector_type(8))) unsigned short ushort8;
typedef __attribute__((ext_vector_type(4))) float f32x4;

static __device__ __forceinline__ unsigned short f2bf(float x) {
    __hip_bfloat16 h = __float2bfloat16(x);
    return __builtin_bit_cast(unsigned short, h);
}

static __device__ __forceinline__ void async_load16(const void* g, void* l) {
    __builtin_amdgcn_global_load_lds(
        (const __attribute__((address_space(1))) unsigned int*)g,
        (__attribute__((address_space(3))) unsigned int*)l, 16, 0, 0);
}

// ---------------------------------------------------------------------------
// fp32 -> bf16 elementwise convert (x)
// ---------------------------------------------------------------------------
__global__ __launch_bounds__(256) void convert_bf16_kernel(
    const float* __restrict__ in, unsigned short* __restrict__ out, int n)
{
    const int idx = (blockIdx.x * 256 + threadIdx.x) * 4;
    if (idx < n) {
        const float4 v = *(const float4*)(in + idx);
        ushort4 u;
        u.x = f2bf(v.x); u.y = f2bf(v.y); u.z = f2bf(v.z); u.w = f2bf(v.w);
        *(ushort4*)(out + idx) = u;
    }
}

// ---------------------------------------------------------------------------
// W [K,N] fp32 -> W^T [N,K] bf16, 64x64 LDS-tiled transpose
// ---------------------------------------------------------------------------
__global__ __launch_bounds__(256) void transpose_bf16_kernel(
    const float* __restrict__ W, unsigned short* __restrict__ Wt, int K, int N)
{
    __shared__ float T[64][65];
    const int tid = threadIdx.x;
    const int tr  = tid >> 4;          // 0..15
    const int tc4 = (tid & 15) * 4;    // 0..60
    const int k0 = blockIdx.y * 64;
    const int n0 = blockIdx.x * 64;

    #pragma unroll
    for (int i = 0; i < 4; ++i) {
        const int kr = i * 16 + tr;
        const float4 v = *(const float4*)(W + (size_t)(k0 + kr) * N + n0 + tc4);
        T[kr][tc4 + 0] = v.x; T[kr][tc4 + 1] = v.y;
        T[kr][tc4 + 2] = v.z; T[kr][tc4 + 3] = v.w;
    }
    __syncthreads();
    #pragma unroll
    for (int i = 0; i < 4; ++i) {
        const int nr = i * 16 + tr;
        ushort4 u;
        u.x = f2bf(T[tc4 + 0][nr]); u.y = f2bf(T[tc4 + 1][nr]);
        u.z = f2bf(T[tc4 + 2][nr]); u.w = f2bf(T[tc4 + 3][nr]);
        *(ushort4*)(Wt + (size_t)(n0 + nr) * K + k0 + tc4) = u;
    }
}

// ---------------------------------------------------------------------------
// MFMA GEMM (m97 structure): C = A[M,K] @ Bt[N,K]^T + bias
// OUTMODE: 0 = fp32 row-major, 1 = bf16 row-major,
//          2 = bf16 transposed into V^T layout [b*16+h][d][s]  (for V)
// ---------------------------------------------------------------------------
template <int OUTMODE>
__global__ __launch_bounds__(256) void gemm_mfma_kernel(
    const unsigned short* __restrict__ A, const unsigned short* __restrict__ Bt,
    const float* __restrict__ bias, void* __restrict__ Cv,
    int M, int N, int K)
{
    __shared__ __align__(16) unsigned short As[128 * 32];
    __shared__ __align__(16) unsigned short Bs[128 * 32];

    const int tid  = threadIdx.x;
    const int lane = tid & 63;
    const int wave = tid >> 6;
    const int ln15 = lane & 15;
    const int quad = lane >> 4;
    const int wm = (wave & 1) * 64;
    const int wn = (wave >> 1) * 64;
    const int bm = blockIdx.y * 128;
    const int bn = blockIdx.x * 128;

    const int srow = tid >> 2;
    const int scol = (tid & 3) * 8;

    const unsigned short* Ap = A  + (size_t)(bm + srow) * K + scol;
    const unsigned short* Bp = Bt + (size_t)(bn + srow) * K + scol;

    f32x4 acc[4][4];
    #pragma unroll
    for (int i = 0; i < 4; ++i)
        #pragma unroll
        for (int j = 0; j < 4; ++j) acc[i][j] = (f32x4){0.f, 0.f, 0.f, 0.f};

    for (int k0 = 0; k0 < K; k0 += 32) {
        __syncthreads();
        async_load16(Ap + k0,                    As + wave * 512);
        async_load16(Ap + (size_t)64 * K + k0,   As + 2048 + wave * 512);
        async_load16(Bp + k0,                    Bs + wave * 512);
        async_load16(Bp + (size_t)64 * K + k0,   Bs + 2048 + wave * 512);
        __syncthreads();

        short8 af[4], bf[4];
        #pragma unroll
        for (int mt = 0; mt < 4; ++mt)
            af[mt] = *(const short8*)(&As[(wm + mt * 16 + ln15) * 32 + quad * 8]);
        #pragma unroll
        for (int nt = 0; nt < 4; ++nt)
            bf[nt] = *(const short8*)(&Bs[(wn + nt * 16 + ln15) * 32 + quad * 8]);
        #pragma unroll
        for (int mt = 0; mt < 4; ++mt)
            #pragma unroll
            for (int nt = 0; nt < 4; ++nt)
                acc[mt][nt] = __builtin_amdgcn_mfma_f32_16x16x32_bf16(
                    af[mt], bf[nt], acc[mt][nt], 0, 0, 0);
    }

    #pragma unroll
    for (int mt = 0; mt < 4; ++mt) {
        if constexpr (OUTMODE == 2) {
            #pragma unroll
            for (int nt = 0; nt < 4; ++nt) {
                const int col = bn + wn + nt * 16 + ln15;
                const int m0  = bm + wm + mt * 16 + quad * 4;
                const int bb  = m0 >> 11;
                const int s0  = m0 & 2047;
                const float bv = bias[col];
                ushort4 pk;
                pk.x = f2bf(acc[mt][nt][0] + bv);
                pk.y = f2bf(acc[mt][nt][1] + bv);
                pk.z = f2bf(acc[mt][nt][2] + bv);
                pk.w = f2bf(acc[mt][nt][3] + bv);
                unsigned short* Vt = (unsigned short*)Cv;
                *(ushort4*)(Vt + ((size_t)(bb * 16 + (col >> 7)) * 128 + (col & 127)) * SEQ + s0) = pk;
            }
        } else {
            #pragma unroll
            for (int r = 0; r < 4; ++r) {
                const int row = bm + wm + mt * 16 + quad * 4 + r;
                #pragma unroll
                for (int nt = 0; nt < 4; ++nt) {
                    const int col = bn + wn + nt * 16 + ln15;
                    const float v = acc[mt][nt][r] + bias[col];
                    if constexpr (OUTMODE == 1)
                        ((unsigned short*)Cv)[(size_t)row * N + col] = f2bf(v);
                    else
                        ((float*)Cv)[(size_t)row * N + col] = v;
                }
            }
        }
    }
}

// ---------------------------------------------------------------------------
// Barrier-free MFMA flash attention, software-pipelined.
// Per 32-key tile: issue V^T loads FIRST (consumed ~250cyc later, after
// S-MFMA + softmax + P LDS roundtrip), then prefetch NEXT tile's K frags
// into the other ping-pong register set. vmcnt is in-order, so using V
// waits vmcnt(8) (K-prefetch stays in flight), and next tile's K use waits
// vmcnt(16) (this tile's V + next prefetch outstanding) — both non-draining.
// No __syncthreads; waves independent. No online max (scores bounded).
// ---------------------------------------------------------------------------
#define P_STRIDE 40

static __device__ __forceinline__ void load_kfrags(
    short8 kf[8], const unsigned short* kp, int kb)
{
    const unsigned short* p = kp + (size_t)kb * DMODEL;
    #pragma unroll
    for (int c = 0; c < 4; ++c) {
        kf[c]     = *(const short8*)(p + c * 32);
        kf[4 + c] = *(const short8*)(p + (size_t)16 * DMODEL + c * 32);
    }
}

static __device__ __forceinline__ void attn_tile(
    int kb, int kbn, int q0w, int ln15, int quad,
    const short8 qf[4], const short8 kcur[8], short8 knext[8],
    const unsigned short* kp, const unsigned short* Vth,
    unsigned short* Pw, f32x4 acc[8], float lsum[4],
    float sc2, float slope2)
{
    // V^T fragments for THIS tile — issued first so waiting on them never
    // drains the K prefetch issued below.
    short8 vf[8];
    #pragma unroll
    for (int nt = 0; nt < 8; ++nt)
        vf[nt] = *(const short8*)(Vth + (size_t)(nt * 16 + ln15) * SEQ + kb + quad * 8);

    // prefetch next tile's K fragments
    load_kfrags(knext, kp, kbn);

    // S = Q K^T using current (already-resident) K frags
    f32x4 s0 = (f32x4){0.f,0.f,0.f,0.f}, s1 = (f32x4){0.f,0.f,0.f,0.f};
    #pragma unroll
    for (int c = 0; c < 4; ++c) {
        s0 = __builtin_amdgcn_mfma_f32_16x16x32_bf16(qf[c], kcur[c],     s0, 0, 0, 0);
        s1 = __builtin_amdgcn_mfma_f32_16x16x32_bf16(qf[c], kcur[4 + c], s1, 0, 0, 0);
    }

    // softmax numerator (no running max; scores bounded)
    float p0[4], p1[4];
    #pragma unroll
    for (int r = 0; r < 4; ++r) {
        const int qrow = q0w + quad * 4 + r;
        const int k0i = kb + ln15;
        const int k1i = kb + 16 + ln15;
        p0[r] = (k0i <= qrow) ? exp2f(s0[r] * sc2 + slope2 * (float)(k0i - qrow)) : 0.f;
        p1[r] = (k1i <= qrow) ? exp2f(s1[r] * sc2 + slope2 * (float)(k1i - qrow)) : 0.f;
        lsum[r] += p0[r] + p1[r];
    }

    // P (C-layout) -> per-wave LDS -> A-layout bf16
    #pragma unroll
    for (int r = 0; r < 4; ++r) {
        Pw[(quad * 4 + r) * P_STRIDE + ln15]      = f2bf(p0[r]);
        Pw[(quad * 4 + r) * P_STRIDE + 16 + ln15] = f2bf(p1[r]);
    }
    __builtin_amdgcn_s_waitcnt(0xC07F);   // lgkmcnt(0) only
    short8 pf = *(const short8*)(&Pw[ln15 * P_STRIDE + quad * 8]);

    // O += P V
    #pragma unroll
    for (int nt = 0; nt < 8; ++nt)
        acc[nt] = __builtin_amdgcn_mfma_f32_16x16x32_bf16(pf, vf[nt], acc[nt], 0, 0, 0);
}

__global__ __launch_bounds__(256) void attn_kernel(
    const unsigned short* __restrict__ Qb, const unsigned short* __restrict__ Kb,
    const unsigned short* __restrict__ Vt,   // [B*H][HDIM][SEQ]
    unsigned short* __restrict__ O)
{
    __shared__ __align__(16) unsigned short Pl[4 * 16 * P_STRIDE];

    const int tid  = threadIdx.x;
    const int lane = tid & 63;
    const int wave = tid >> 6;
    const int ln15 = lane & 15;
    const int quad = lane >> 4;
    const int h = blockIdx.y;
    const int b = blockIdx.z;
    const int qblk = gridDim.x - 1 - blockIdx.x;   // big blocks first
    const int q0w  = qblk * 64 + wave * 16;

    const size_t rowbase = (size_t)b * SEQ;
    const size_t hoff    = (size_t)h * HDIM;
    const unsigned short* Vth = Vt + (size_t)(b * NHEADS + h) * HDIM * SEQ;

    const float sc2    = 0.08838834764831845f * 1.4426950408889634f;
    const float slope2 = exp2f(-0.5f * (float)(h + 1)) * 1.4426950408889634f;

    // Q fragments (A-layout), 4 k-chunks of 32
    short8 qf[4];
    {
        const unsigned short* qp =
            Qb + (rowbase + q0w + ln15) * DMODEL + hoff + quad * 8;
        qf[0] = *(const short8*)(qp);
        qf[1] = *(const short8*)(qp + 32);
        qf[2] = *(const short8*)(qp + 64);
        qf[3] = *(const short8*)(qp + 96);
    }

    f32x4 acc[8];
    #pragma unroll
    for (int nt = 0; nt < 8; ++nt) acc[nt] = (f32x4){0.f, 0.f, 0.f, 0.f};
    float lsum[4] = {0.f, 0.f, 0.f, 0.f};

    unsigned short* Pw = &Pl[wave * 16 * P_STRIDE];
    const unsigned short* kp = Kb + (rowbase + ln15) * DMODEL + hoff + quad * 8;

    const int ntiles = (q0w + 47) >> 5;   // ceil((q0w+16)/32) >= 1

    short8 kA[8], kB[8];
    load_kfrags(kA, kp, 0);

    int t = 0;
    for (;;) {
        {
            const int kbn = (t + 1 < ntiles ? t + 1 : t) * 32;
            attn_tile(t * 32, kbn, q0w, ln15, quad, qf, kA, kB, kp, Vth,
                      Pw, acc, lsum, sc2, slope2);
        }
        if (++t == ntiles) break;
        {
            const int kbn = (t + 1 < ntiles ? t + 1 : t) * 32;
            attn_tile(t * 32, kbn, q0w, ln15, quad, qf, kB, kA, kp, Vth,
                      Pw, acc, lsum, sc2, slope2);
        }
        if (++t == ntiles) break;
    }

    // finalize: reduce l across the 16 lanes of each row, store O
    #pragma unroll
    for (int r = 0; r < 4; ++r) {
        float l = lsum[r];
        l += __shfl_xor(l, 1, 64);
        l += __shfl_xor(l, 2, 64);
        l += __shfl_xor(l, 4, 64);
        l += __shfl_xor(l, 8, 64);
        const float inv = 1.0f / l;
        const size_t ob = (rowbase + q0w + quad * 4 + r) * DMODEL + hoff;
        #pragma unroll
        for (int nt = 0; nt < 8; ++nt)
            O[ob + nt * 16 + ln15] = f2bf(acc[nt][r] * inv);
    }
}

// ---------------------------------------------------------------------------
extern "C" void kernel_launch(void* const* d_in, const int* in_sizes, int n_in,
                              void* d_out, int out_size, void* d_ws, size_t ws_size,
                              hipStream_t stream)
{
    const float* x  = (const float*)d_in[0];
    const float* wq = (const float*)d_in[1];
    const float* bq = (const float*)d_in[2];
    const float* wk = (const float*)d_in[3];
    const float* bk = (const float*)d_in[4];
    const float* wv = (const float*)d_in[5];
    const float* bv = (const float*)d_in[6];
    const float* wo = (const float*)d_in[7];
    const float* bo = (const float*)d_in[8];
    float* out = (float*)d_out;

    const size_t bufElems = (size_t)MROWS * DMODEL;   // 8.39M
    unsigned short* Qb  = (unsigned short*)d_ws;
    unsigned short* Kb  = Qb + bufElems;
    unsigned short* Vtg = Kb + bufElems;   // V^T: [B*H][HDIM][SEQ]
    unsigned short* Ob  = Vtg + bufElems;
    unsigned short* xb  = Ob + bufElems;
    unsigned short* Wt  = xb + bufElems;   // 2048*2048, reused per weight

    const dim3 cvtGrid((int)(bufElems / 1024));
    const dim3 trGrid(DMODEL / 64, DMODEL / 64);
    const dim3 gemmGrid(DMODEL / 128, MROWS / 128);   // (16, 32)
    const dim3 blk(256);

    convert_bf16_kernel<<<cvtGrid, blk, 0, stream>>>(x, xb, (int)bufElems);

    transpose_bf16_kernel<<<trGrid, blk, 0, stream>>>(wq, Wt, DMODEL, DMODEL);
    gemm_mfma_kernel<1><<<gemmGrid, blk, 0, stream>>>(xb, Wt, bq, Qb, MROWS, DMODEL, DMODEL);
    transpose_bf16_kernel<<<trGrid, blk, 0, stream>>>(wk, Wt, DMODEL, DMODEL);
    gemm_mfma_kernel<1><<<gemmGrid, blk, 0, stream>>>(xb, Wt, bk, Kb, MROWS, DMODEL, DMODEL);
    transpose_bf16_kernel<<<trGrid, blk, 0, stream>>>(wv, Wt, DMODEL, DMODEL);
    gemm_mfma_kernel<2><<<gemmGrid, blk, 0, stream>>>(xb, Wt, bv, Vtg, MROWS, DMODEL, DMODEL);

    const dim3 attnGrid(SEQ / 64, NHEADS, BATCH);
    attn_kernel<<<attnGrid, blk, 0, stream>>>(Qb, Kb, Vtg, Ob);

    transpose_bf16_kernel<<<trGrid, blk, 0, stream>>>(wo, Wt, DMODEL, DMODEL);
    gemm_mfma_kernel<0><<<gemmGrid, blk, 0, stream>>>(Ob, Wt, bo, out, MROWS, DMODEL, DMODEL);
}

// Round 6
// 474.232 us; speedup vs baseline: 1.7269x; 1.7269x over previous
//
#include <hip/hip_runtime.h>
#include <hip/hip_bf16.h>
#include <math.h>

// Problem constants (fixed by reference)
#define BATCH 2
#define SEQ   2048
#define DMODEL 2048
#define NHEADS 16
#define HDIM  128
#define MROWS (BATCH * SEQ)   // 4096

typedef __attribute__((ext_vector_type(8))) short short8;
typedef __attribute__((ext_vector_type(8))) unsigned short ushort8;
typedef __attribute__((ext_vector_type(4))) float f32x4;

static __device__ __forceinline__ unsigned short f2bf(float x) {
    __hip_bfloat16 h = __float2bfloat16(x);
    return __builtin_bit_cast(unsigned short, h);
}

static __device__ __forceinline__ void async_load16(const void* g, void* l) {
    __builtin_amdgcn_global_load_lds(
        (const __attribute__((address_space(1))) unsigned int*)g,
        (__attribute__((address_space(3))) unsigned int*)l, 16, 0, 0);
}

// ---------------------------------------------------------------------------
// fp32 -> bf16 elementwise convert (x)
// ---------------------------------------------------------------------------
__global__ __launch_bounds__(256) void convert_bf16_kernel(
    const float* __restrict__ in, unsigned short* __restrict__ out, int n)
{
    const int idx = (blockIdx.x * 256 + threadIdx.x) * 4;
    if (idx < n) {
        const float4 v = *(const float4*)(in + idx);
        ushort4 u;
        u.x = f2bf(v.x); u.y = f2bf(v.y); u.z = f2bf(v.z); u.w = f2bf(v.w);
        *(ushort4*)(out + idx) = u;
    }
}

// ---------------------------------------------------------------------------
// W [K,N] fp32 -> W^T [N,K] bf16, 64x64 LDS-tiled transpose
// ---------------------------------------------------------------------------
__global__ __launch_bounds__(256) void transpose_bf16_kernel(
    const float* __restrict__ W, unsigned short* __restrict__ Wt, int K, int N)
{
    __shared__ float T[64][65];
    const int tid = threadIdx.x;
    const int tr  = tid >> 4;          // 0..15
    const int tc4 = (tid & 15) * 4;    // 0..60
    const int k0 = blockIdx.y * 64;
    const int n0 = blockIdx.x * 64;

    #pragma unroll
    for (int i = 0; i < 4; ++i) {
        const int kr = i * 16 + tr;
        const float4 v = *(const float4*)(W + (size_t)(k0 + kr) * N + n0 + tc4);
        T[kr][tc4 + 0] = v.x; T[kr][tc4 + 1] = v.y;
        T[kr][tc4 + 2] = v.z; T[kr][tc4 + 3] = v.w;
    }
    __syncthreads();
    #pragma unroll
    for (int i = 0; i < 4; ++i) {
        const int nr = i * 16 + tr;
        ushort4 u;
        u.x = f2bf(T[tc4 + 0][nr]); u.y = f2bf(T[tc4 + 1][nr]);
        u.z = f2bf(T[tc4 + 2][nr]); u.w = f2bf(T[tc4 + 3][nr]);
        *(ushort4*)(Wt + (size_t)(n0 + nr) * K + k0 + tc4) = u;
    }
}

// ---------------------------------------------------------------------------
// MFMA GEMM (m97 structure): C = A[M,K] @ Bt[N,K]^T + bias
// OUTMODE: 0 = fp32 row-major, 1 = bf16 row-major,
//          2 = bf16 transposed into V^T layout [b*16+h][d][s]  (for V)
// ---------------------------------------------------------------------------
template <int OUTMODE>
__global__ __launch_bounds__(256) void gemm_mfma_kernel(
    const unsigned short* __restrict__ A, const unsigned short* __restrict__ Bt,
    const float* __restrict__ bias, void* __restrict__ Cv,
    int M, int N, int K)
{
    __shared__ __align__(16) unsigned short As[128 * 32];
    __shared__ __align__(16) unsigned short Bs[128 * 32];

    const int tid  = threadIdx.x;
    const int lane = tid & 63;
    const int wave = tid >> 6;
    const int ln15 = lane & 15;
    const int quad = lane >> 4;
    const int wm = (wave & 1) * 64;
    const int wn = (wave >> 1) * 64;
    const int bm = blockIdx.y * 128;
    const int bn = blockIdx.x * 128;

    const int srow = tid >> 2;
    const int scol = (tid & 3) * 8;

    const unsigned short* Ap = A  + (size_t)(bm + srow) * K + scol;
    const unsigned short* Bp = Bt + (size_t)(bn + srow) * K + scol;

    f32x4 acc[4][4];
    #pragma unroll
    for (int i = 0; i < 4; ++i)
        #pragma unroll
        for (int j = 0; j < 4; ++j) acc[i][j] = (f32x4){0.f, 0.f, 0.f, 0.f};

    for (int k0 = 0; k0 < K; k0 += 32) {
        __syncthreads();
        async_load16(Ap + k0,                    As + wave * 512);
        async_load16(Ap + (size_t)64 * K + k0,   As + 2048 + wave * 512);
        async_load16(Bp + k0,                    Bs + wave * 512);
        async_load16(Bp + (size_t)64 * K + k0,   Bs + 2048 + wave * 512);
        __syncthreads();

        short8 af[4], bf[4];
        #pragma unroll
        for (int mt = 0; mt < 4; ++mt)
            af[mt] = *(const short8*)(&As[(wm + mt * 16 + ln15) * 32 + quad * 8]);
        #pragma unroll
        for (int nt = 0; nt < 4; ++nt)
            bf[nt] = *(const short8*)(&Bs[(wn + nt * 16 + ln15) * 32 + quad * 8]);
        #pragma unroll
        for (int mt = 0; mt < 4; ++mt)
            #pragma unroll
            for (int nt = 0; nt < 4; ++nt)
                acc[mt][nt] = __builtin_amdgcn_mfma_f32_16x16x32_bf16(
                    af[mt], bf[nt], acc[mt][nt], 0, 0, 0);
    }

    #pragma unroll
    for (int mt = 0; mt < 4; ++mt) {
        if constexpr (OUTMODE == 2) {
            #pragma unroll
            for (int nt = 0; nt < 4; ++nt) {
                const int col = bn + wn + nt * 16 + ln15;
                const int m0  = bm + wm + mt * 16 + quad * 4;
                const int bb  = m0 >> 11;
                const int s0  = m0 & 2047;
                const float bv = bias[col];
                ushort4 pk;
                pk.x = f2bf(acc[mt][nt][0] + bv);
                pk.y = f2bf(acc[mt][nt][1] + bv);
                pk.z = f2bf(acc[mt][nt][2] + bv);
                pk.w = f2bf(acc[mt][nt][3] + bv);
                unsigned short* Vt = (unsigned short*)Cv;
                *(ushort4*)(Vt + ((size_t)(bb * 16 + (col >> 7)) * 128 + (col & 127)) * SEQ + s0) = pk;
            }
        } else {
            #pragma unroll
            for (int r = 0; r < 4; ++r) {
                const int row = bm + wm + mt * 16 + quad * 4 + r;
                #pragma unroll
                for (int nt = 0; nt < 4; ++nt) {
                    const int col = bn + wn + nt * 16 + ln15;
                    const float v = acc[mt][nt][r] + bias[col];
                    if constexpr (OUTMODE == 1)
                        ((unsigned short*)Cv)[(size_t)row * N + col] = f2bf(v);
                    else
                        ((float*)Cv)[(size_t)row * N + col] = v;
                }
            }
        }
    }
}

// ---------------------------------------------------------------------------
// MFMA flash attention w/ ALiBi + causal — LDS-staged, double-buffered,
// pair-balanced.
//   * Block j processes q-block j then (31-j): uniform 66 tiles/block.
//   * K tile (32 keys x 128 dims) and V^T tile (128 dims x 32 keys) staged
//     via global_load_lds width-16 (contiguous; V pre-transposed in global).
//     Since LDS dest is forced base+lane*16, bank-swizzle is applied on the
//     GLOBAL side: LDS 16B-slot s of key-row k holds global chunk s^(k&15)
//     (V rows: s^((dim>>1)&3)); fragment reads XOR identically -> 2-way
//     bank access (free), no padding.
//   * Single barrier per tile: stage(t+1,buf^1); compute(t,buf); barrier.
//   * No online max (scores bounded); normalize by l at the end.
// ---------------------------------------------------------------------------
#define ATT_P_STRIDE 40

__global__ __launch_bounds__(256) void attn_kernel(
    const unsigned short* __restrict__ Qb, const unsigned short* __restrict__ Kb,
    const unsigned short* __restrict__ Vt,   // [B*H][HDIM][SEQ]
    unsigned short* __restrict__ O)
{
    __shared__ __align__(16) unsigned short Ks[2][32 * 128];
    __shared__ __align__(16) unsigned short Vs[2][128 * 32];
    __shared__ __align__(16) unsigned short Pl[4 * 16 * ATT_P_STRIDE];

    const int tid  = threadIdx.x;
    const int lane = tid & 63;
    const int wave = tid >> 6;
    const int ln15 = lane & 15;
    const int quad = lane >> 4;
    const int h = blockIdx.y;
    const int b = blockIdx.z;

    const size_t rowbase = (size_t)b * SEQ;
    const size_t hoff    = (size_t)h * HDIM;
    const unsigned short* Kh  = Kb + rowbase * DMODEL + hoff;
    const unsigned short* Vth = Vt + (size_t)(b * NHEADS + h) * HDIM * SEQ;

    const float sc2    = 0.08838834764831845f * 1.4426950408889634f;
    const float slope2 = exp2f(-0.5f * (float)(h + 1)) * 1.4426950408889634f;

    // staging lane roles
    const int kq  = wave * 8 + (lane >> 4);   // K: key row (instr0; +4 instr1)
    const int ksl = lane & 15;                //    16B slot within 256B row
    const int dq  = wave * 32 + (lane >> 2);  // V: dim row (instr0; +16 instr1)
    const int vsl = lane & 3;                 //    16B slot within 64B row
    const int vsw = (ln15 >> 1) & 3;          // V frag-read swizzle

    unsigned short* Pw = &Pl[wave * 16 * ATT_P_STRIDE];

    #pragma unroll 1
    for (int ph = 0; ph < 2; ++ph) {
        const int qblk = ph ? (31 - (int)blockIdx.x) : (int)blockIdx.x;
        const int q0w  = qblk * 64 + wave * 16;
        const int nT   = 2 * qblk + 2;

        // Q fragments (A-layout), 4 k-chunks of 32
        short8 qf[4];
        {
            const unsigned short* qp =
                Qb + (rowbase + q0w + ln15) * DMODEL + hoff + quad * 8;
            qf[0] = *(const short8*)(qp);
            qf[1] = *(const short8*)(qp + 32);
            qf[2] = *(const short8*)(qp + 64);
            qf[3] = *(const short8*)(qp + 96);
        }

        f32x4 acc[8];
        #pragma unroll
        for (int nt = 0; nt < 8; ++nt) acc[nt] = (f32x4){0.f, 0.f, 0.f, 0.f};
        float lsum[4] = {0.f, 0.f, 0.f, 0.f};

        // ---- stage tile 0 into buffer 0 ----
        {
            #pragma unroll
            for (int i = 0; i < 2; ++i) {
                const int k = kq + i * 4;
                async_load16(Kh + (size_t)k * DMODEL + (ksl ^ (k & 15)) * 8,
                             &Ks[0][(wave * 8 + i * 4) * 128]);
            }
            #pragma unroll
            for (int i = 0; i < 2; ++i) {
                const int d = dq + i * 16;
                async_load16(Vth + (size_t)d * SEQ + (vsl ^ ((d >> 1) & 3)) * 8,
                             &Vs[0][(wave * 32 + i * 16) * 32]);
            }
        }
        __syncthreads();

        for (int t = 0; t < nT; ++t) {
            const int kb  = t * 32;
            const int buf = t & 1;

            // ---- stage tile t+1 into the other buffer (async) ----
            if (t + 1 < nT) {
                const int kb1 = kb + 32;
                #pragma unroll
                for (int i = 0; i < 2; ++i) {
                    const int k = kq + i * 4;
                    async_load16(Kh + (size_t)(kb1 + k) * DMODEL + (ksl ^ (k & 15)) * 8,
                                 &Ks[buf ^ 1][(wave * 8 + i * 4) * 128]);
                }
                #pragma unroll
                for (int i = 0; i < 2; ++i) {
                    const int d = dq + i * 16;
                    async_load16(Vth + (size_t)d * SEQ + kb1 + (vsl ^ ((d >> 1) & 3)) * 8,
                                 &Vs[buf ^ 1][(wave * 32 + i * 16) * 32]);
                }
            }

            // ---- compute tile t (waves with no unmasked keys skip) ----
            if (kb <= q0w + 15) {
                const unsigned short* KsB = Ks[buf];
                const unsigned short* VsB = Vs[buf];

                f32x4 s0 = (f32x4){0.f,0.f,0.f,0.f}, s1 = (f32x4){0.f,0.f,0.f,0.f};
                #pragma unroll
                for (int c = 0; c < 4; ++c) {
                    const int slot = (c * 4 + quad) ^ ln15;
                    short8 kf0 = *(const short8*)(&KsB[ln15 * 128 + slot * 8]);
                    short8 kf1 = *(const short8*)(&KsB[(16 + ln15) * 128 + slot * 8]);
                    s0 = __builtin_amdgcn_mfma_f32_16x16x32_bf16(qf[c], kf0, s0, 0, 0, 0);
                    s1 = __builtin_amdgcn_mfma_f32_16x16x32_bf16(qf[c], kf1, s1, 0, 0, 0);
                }

                float p0[4], p1[4];
                #pragma unroll
                for (int r = 0; r < 4; ++r) {
                    const int qrow = q0w + quad * 4 + r;
                    const int k0i = kb + ln15;
                    const int k1i = kb + 16 + ln15;
                    p0[r] = (k0i <= qrow)
                          ? exp2f(s0[r] * sc2 + slope2 * (float)(k0i - qrow)) : 0.f;
                    p1[r] = (k1i <= qrow)
                          ? exp2f(s1[r] * sc2 + slope2 * (float)(k1i - qrow)) : 0.f;
                    lsum[r] += p0[r] + p1[r];
                }

                #pragma unroll
                for (int r = 0; r < 4; ++r) {
                    Pw[(quad * 4 + r) * ATT_P_STRIDE + ln15]      = f2bf(p0[r]);
                    Pw[(quad * 4 + r) * ATT_P_STRIDE + 16 + ln15] = f2bf(p1[r]);
                }
                __builtin_amdgcn_s_waitcnt(0xC07F);   // lgkmcnt(0) only
                short8 pf = *(const short8*)(&Pw[ln15 * ATT_P_STRIDE + quad * 8]);

                #pragma unroll
                for (int nt = 0; nt < 8; ++nt) {
                    short8 vf = *(const short8*)(
                        &VsB[(nt * 16 + ln15) * 32 + (quad ^ vsw) * 8]);
                    acc[nt] = __builtin_amdgcn_mfma_f32_16x16x32_bf16(pf, vf, acc[nt], 0, 0, 0);
                }
            }
            __syncthreads();
        }

        // ---- finalize: reduce l across the 16 lanes of each row, store O ----
        #pragma unroll
        for (int r = 0; r < 4; ++r) {
            float l = lsum[r];
            l += __shfl_xor(l, 1, 64);
            l += __shfl_xor(l, 2, 64);
            l += __shfl_xor(l, 4, 64);
            l += __shfl_xor(l, 8, 64);
            const float inv = 1.0f / l;
            const size_t ob = (rowbase + q0w + quad * 4 + r) * DMODEL + hoff;
            #pragma unroll
            for (int nt = 0; nt < 8; ++nt)
                O[ob + nt * 16 + ln15] = f2bf(acc[nt][r] * inv);
        }
    }
}

// ---------------------------------------------------------------------------
extern "C" void kernel_launch(void* const* d_in, const int* in_sizes, int n_in,
                              void* d_out, int out_size, void* d_ws, size_t ws_size,
                              hipStream_t stream)
{
    const float* x  = (const float*)d_in[0];
    const float* wq = (const float*)d_in[1];
    const float* bq = (const float*)d_in[2];
    const float* wk = (const float*)d_in[3];
    const float* bk = (const float*)d_in[4];
    const float* wv = (const float*)d_in[5];
    const float* bv = (const float*)d_in[6];
    const float* wo = (const float*)d_in[7];
    const float* bo = (const float*)d_in[8];
    float* out = (float*)d_out;

    const size_t bufElems = (size_t)MROWS * DMODEL;   // 8.39M
    unsigned short* Qb  = (unsigned short*)d_ws;
    unsigned short* Kb  = Qb + bufElems;
    unsigned short* Vtg = Kb + bufElems;   // V^T: [B*H][HDIM][SEQ]
    unsigned short* Ob  = Vtg + bufElems;
    unsigned short* xb  = Ob + bufElems;
    unsigned short* Wt  = xb + bufElems;   // 2048*2048, reused per weight

    const dim3 cvtGrid((int)(bufElems / 1024));
    const dim3 trGrid(DMODEL / 64, DMODEL / 64);
    const dim3 gemmGrid(DMODEL / 128, MROWS / 128);   // (16, 32)
    const dim3 blk(256);

    convert_bf16_kernel<<<cvtGrid, blk, 0, stream>>>(x, xb, (int)bufElems);

    transpose_bf16_kernel<<<trGrid, blk, 0, stream>>>(wq, Wt, DMODEL, DMODEL);
    gemm_mfma_kernel<1><<<gemmGrid, blk, 0, stream>>>(xb, Wt, bq, Qb, MROWS, DMODEL, DMODEL);
    transpose_bf16_kernel<<<trGrid, blk, 0, stream>>>(wk, Wt, DMODEL, DMODEL);
    gemm_mfma_kernel<1><<<gemmGrid, blk, 0, stream>>>(xb, Wt, bk, Kb, MROWS, DMODEL, DMODEL);
    transpose_bf16_kernel<<<trGrid, blk, 0, stream>>>(wv, Wt, DMODEL, DMODEL);
    gemm_mfma_kernel<2><<<gemmGrid, blk, 0, stream>>>(xb, Wt, bv, Vtg, MROWS, DMODEL, DMODEL);

    const dim3 attnGrid(16, NHEADS, BATCH);   // 512 uniform blocks (paired)
    attn_kernel<<<attnGrid, blk, 0, stream>>>(Qb, Kb, Vtg, Ob);

    transpose_bf16_kernel<<<trGrid, blk, 0, stream>>>(wo, Wt, DMODEL, DMODEL);
    gemm_mfma_kernel<0><<<gemmGrid, blk, 0, stream>>>(Ob, Wt, bo, out, MROWS, DMODEL, DMODEL);
}

// Round 7
// 427.504 us; speedup vs baseline: 1.9157x; 1.1093x over previous
//
#include <hip/hip_runtime.h>
#include <hip/hip_bf16.h>
#include <math.h>

// Problem constants (fixed by reference)
#define BATCH 2
#define SEQ   2048
#define DMODEL 2048
#define NHEADS 16
#define HDIM  128
#define MROWS (BATCH * SEQ)   // 4096

typedef __attribute__((ext_vector_type(8))) short short8;
typedef __attribute__((ext_vector_type(8))) unsigned short ushort8;
typedef __attribute__((ext_vector_type(4))) float f32x4;

static __device__ __forceinline__ unsigned short f2bf(float x) {
    __hip_bfloat16 h = __float2bfloat16(x);
    return __builtin_bit_cast(unsigned short, h);
}

static __device__ __forceinline__ void async_load16(const void* g, void* l) {
    __builtin_amdgcn_global_load_lds(
        (const __attribute__((address_space(1))) unsigned int*)g,
        (__attribute__((address_space(3))) unsigned int*)l, 16, 0, 0);
}

// ---------------------------------------------------------------------------
// fp32 -> bf16 elementwise convert (x)
// ---------------------------------------------------------------------------
__global__ __launch_bounds__(256) void convert_bf16_kernel(
    const float* __restrict__ in, unsigned short* __restrict__ out, int n)
{
    const int idx = (blockIdx.x * 256 + threadIdx.x) * 4;
    if (idx < n) {
        const float4 v = *(const float4*)(in + idx);
        ushort4 u;
        u.x = f2bf(v.x); u.y = f2bf(v.y); u.z = f2bf(v.z); u.w = f2bf(v.w);
        *(ushort4*)(out + idx) = u;
    }
}

// ---------------------------------------------------------------------------
// Fused transpose of wq,wk,wv: [K,N] fp32 -> [N,K] bf16 into 3 Wt slots.
// ---------------------------------------------------------------------------
__global__ __launch_bounds__(256) void transpose3_bf16_kernel(
    const float* __restrict__ w0, const float* __restrict__ w1,
    const float* __restrict__ w2, unsigned short* __restrict__ WtAll)
{
    const float* W = blockIdx.z == 0 ? w0 : (blockIdx.z == 1 ? w1 : w2);
    unsigned short* Wt = WtAll + (size_t)blockIdx.z * DMODEL * DMODEL;

    __shared__ float T[64][65];
    const int tid = threadIdx.x;
    const int tr  = tid >> 4;
    const int tc4 = (tid & 15) * 4;
    const int k0 = blockIdx.y * 64;
    const int n0 = blockIdx.x * 64;

    #pragma unroll
    for (int i = 0; i < 4; ++i) {
        const int kr = i * 16 + tr;
        const float4 v = *(const float4*)(W + (size_t)(k0 + kr) * DMODEL + n0 + tc4);
        T[kr][tc4 + 0] = v.x; T[kr][tc4 + 1] = v.y;
        T[kr][tc4 + 2] = v.z; T[kr][tc4 + 3] = v.w;
    }
    __syncthreads();
    #pragma unroll
    for (int i = 0; i < 4; ++i) {
        const int nr = i * 16 + tr;
        ushort4 u;
        u.x = f2bf(T[tc4 + 0][nr]); u.y = f2bf(T[tc4 + 1][nr]);
        u.z = f2bf(T[tc4 + 2][nr]); u.w = f2bf(T[tc4 + 3][nr]);
        *(ushort4*)(Wt + (size_t)(n0 + nr) * DMODEL + k0 + tc4) = u;
    }
}

// single transpose (for wo)
__global__ __launch_bounds__(256) void transpose_bf16_kernel(
    const float* __restrict__ W, unsigned short* __restrict__ Wt, int K, int N)
{
    __shared__ float T[64][65];
    const int tid = threadIdx.x;
    const int tr  = tid >> 4;
    const int tc4 = (tid & 15) * 4;
    const int k0 = blockIdx.y * 64;
    const int n0 = blockIdx.x * 64;

    #pragma unroll
    for (int i = 0; i < 4; ++i) {
        const int kr = i * 16 + tr;
        const float4 v = *(const float4*)(W + (size_t)(k0 + kr) * N + n0 + tc4);
        T[kr][tc4 + 0] = v.x; T[kr][tc4 + 1] = v.y;
        T[kr][tc4 + 2] = v.z; T[kr][tc4 + 3] = v.w;
    }
    __syncthreads();
    #pragma unroll
    for (int i = 0; i < 4; ++i) {
        const int nr = i * 16 + tr;
        ushort4 u;
        u.x = f2bf(T[tc4 + 0][nr]); u.y = f2bf(T[tc4 + 1][nr]);
        u.z = f2bf(T[tc4 + 2][nr]); u.w = f2bf(T[tc4 + 3][nr]);
        *(ushort4*)(Wt + (size_t)(n0 + nr) * K + k0 + tc4) = u;
    }
}

// ---------------------------------------------------------------------------
// Fused QKV MFMA GEMM: one dispatch, N = 3*2048. Block column range selects
// projection (widx = bn>>11): Q,K -> row-major bf16; V -> V^T layout
// [b*16+h][d][s]. m97 structure, 128x128 tile, BK=32.
// ---------------------------------------------------------------------------
__global__ __launch_bounds__(256) void qkv_gemm_kernel(
    const unsigned short* __restrict__ A, const unsigned short* __restrict__ WtAll,
    const float* __restrict__ bq, const float* __restrict__ bk,
    const float* __restrict__ bv,
    unsigned short* __restrict__ Qb, unsigned short* __restrict__ Kb,
    unsigned short* __restrict__ Vt)
{
    constexpr int K = DMODEL;
    __shared__ __align__(16) unsigned short As[128 * 32];
    __shared__ __align__(16) unsigned short Bs[128 * 32];

    const int tid  = threadIdx.x;
    const int lane = tid & 63;
    const int wave = tid >> 6;
    const int ln15 = lane & 15;
    const int quad = lane >> 4;
    const int wm = (wave & 1) * 64;
    const int wn = (wave >> 1) * 64;
    const int bm = blockIdx.y * 128;
    const int bn = blockIdx.x * 128;           // 0..6016
    const int widx = bn >> 11;                 // 0=Q 1=K 2=V
    const int bnl  = bn & 2047;

    const unsigned short* Bt = WtAll + (size_t)widx * DMODEL * DMODEL;
    const float* bias = widx == 0 ? bq : (widx == 1 ? bk : bv);

    const int srow = tid >> 2;
    const int scol = (tid & 3) * 8;

    const unsigned short* Ap = A  + (size_t)(bm + srow) * K + scol;
    const unsigned short* Bp = Bt + (size_t)(bnl + srow) * K + scol;

    f32x4 acc[4][4];
    #pragma unroll
    for (int i = 0; i < 4; ++i)
        #pragma unroll
        for (int j = 0; j < 4; ++j) acc[i][j] = (f32x4){0.f, 0.f, 0.f, 0.f};

    for (int k0 = 0; k0 < K; k0 += 32) {
        __syncthreads();
        async_load16(Ap + k0,                    As + wave * 512);
        async_load16(Ap + (size_t)64 * K + k0,   As + 2048 + wave * 512);
        async_load16(Bp + k0,                    Bs + wave * 512);
        async_load16(Bp + (size_t)64 * K + k0,   Bs + 2048 + wave * 512);
        __syncthreads();

        short8 af[4], bf[4];
        #pragma unroll
        for (int mt = 0; mt < 4; ++mt)
            af[mt] = *(const short8*)(&As[(wm + mt * 16 + ln15) * 32 + quad * 8]);
        #pragma unroll
        for (int nt = 0; nt < 4; ++nt)
            bf[nt] = *(const short8*)(&Bs[(wn + nt * 16 + ln15) * 32 + quad * 8]);
        #pragma unroll
        for (int mt = 0; mt < 4; ++mt)
            #pragma unroll
            for (int nt = 0; nt < 4; ++nt)
                acc[mt][nt] = __builtin_amdgcn_mfma_f32_16x16x32_bf16(
                    af[mt], bf[nt], acc[mt][nt], 0, 0, 0);
    }

    if (widx == 2) {
        #pragma unroll
        for (int mt = 0; mt < 4; ++mt)
            #pragma unroll
            for (int nt = 0; nt < 4; ++nt) {
                const int col = bnl + wn + nt * 16 + ln15;     // 0..2047
                const int m0  = bm + wm + mt * 16 + quad * 4;
                const int bb  = m0 >> 11;
                const int s0  = m0 & 2047;
                const float bvv = bias[col];
                ushort4 pk;
                pk.x = f2bf(acc[mt][nt][0] + bvv);
                pk.y = f2bf(acc[mt][nt][1] + bvv);
                pk.z = f2bf(acc[mt][nt][2] + bvv);
                pk.w = f2bf(acc[mt][nt][3] + bvv);
                *(ushort4*)(Vt + ((size_t)(bb * 16 + (col >> 7)) * 128 + (col & 127)) * SEQ + s0) = pk;
            }
    } else {
        unsigned short* dst = widx ? Kb : Qb;
        #pragma unroll
        for (int mt = 0; mt < 4; ++mt)
            #pragma unroll
            for (int r = 0; r < 4; ++r) {
                const int row = bm + wm + mt * 16 + quad * 4 + r;
                #pragma unroll
                for (int nt = 0; nt < 4; ++nt) {
                    const int col = bnl + wn + nt * 16 + ln15;
                    dst[(size_t)row * DMODEL + col] = f2bf(acc[mt][nt][r] + bias[col]);
                }
            }
    }
}

// ---------------------------------------------------------------------------
// Out-projection MFMA GEMM (fp32 out), m97 structure.
// ---------------------------------------------------------------------------
__global__ __launch_bounds__(256) void gemm_out_kernel(
    const unsigned short* __restrict__ A, const unsigned short* __restrict__ Bt,
    const float* __restrict__ bias, float* __restrict__ C, int M, int N, int K)
{
    __shared__ __align__(16) unsigned short As[128 * 32];
    __shared__ __align__(16) unsigned short Bs[128 * 32];

    const int tid  = threadIdx.x;
    const int lane = tid & 63;
    const int wave = tid >> 6;
    const int ln15 = lane & 15;
    const int quad = lane >> 4;
    const int wm = (wave & 1) * 64;
    const int wn = (wave >> 1) * 64;
    const int bm = blockIdx.y * 128;
    const int bn = blockIdx.x * 128;

    const int srow = tid >> 2;
    const int scol = (tid & 3) * 8;

    const unsigned short* Ap = A  + (size_t)(bm + srow) * K + scol;
    const unsigned short* Bp = Bt + (size_t)(bn + srow) * K + scol;

    f32x4 acc[4][4];
    #pragma unroll
    for (int i = 0; i < 4; ++i)
        #pragma unroll
        for (int j = 0; j < 4; ++j) acc[i][j] = (f32x4){0.f, 0.f, 0.f, 0.f};

    for (int k0 = 0; k0 < K; k0 += 32) {
        __syncthreads();
        async_load16(Ap + k0,                    As + wave * 512);
        async_load16(Ap + (size_t)64 * K + k0,   As + 2048 + wave * 512);
        async_load16(Bp + k0,                    Bs + wave * 512);
        async_load16(Bp + (size_t)64 * K + k0,   Bs + 2048 + wave * 512);
        __syncthreads();

        short8 af[4], bf[4];
        #pragma unroll
        for (int mt = 0; mt < 4; ++mt)
            af[mt] = *(const short8*)(&As[(wm + mt * 16 + ln15) * 32 + quad * 8]);
        #pragma unroll
        for (int nt = 0; nt < 4; ++nt)
            bf[nt] = *(const short8*)(&Bs[(wn + nt * 16 + ln15) * 32 + quad * 8]);
        #pragma unroll
        for (int mt = 0; mt < 4; ++mt)
            #pragma unroll
            for (int nt = 0; nt < 4; ++nt)
                acc[mt][nt] = __builtin_amdgcn_mfma_f32_16x16x32_bf16(
                    af[mt], bf[nt], acc[mt][nt], 0, 0, 0);
    }

    #pragma unroll
    for (int mt = 0; mt < 4; ++mt)
        #pragma unroll
        for (int r = 0; r < 4; ++r) {
            const int row = bm + wm + mt * 16 + quad * 4 + r;
            #pragma unroll
            for (int nt = 0; nt < 4; ++nt) {
                const int col = bn + wn + nt * 16 + ln15;
                C[(size_t)row * N + col] = acc[mt][nt][r] + bias[col];
            }
        }
}

// ---------------------------------------------------------------------------
// MFMA flash attention — LDS-staged, double-buffered, pair-balanced,
// fast-path/diagonal split, XCD-pinned (blocks of one head ≡ same id mod 32
// -> same XCD under round-robin dispatch).
// ---------------------------------------------------------------------------
#define ATT_P_STRIDE 40

__global__ __launch_bounds__(256) void attn_kernel(
    const unsigned short* __restrict__ Qb, const unsigned short* __restrict__ Kb,
    const unsigned short* __restrict__ Vt,   // [B*H][HDIM][SEQ]
    unsigned short* __restrict__ O)
{
    __shared__ __align__(16) unsigned short Ks[2][32 * 128];
    __shared__ __align__(16) unsigned short Vs[2][128 * 32];
    __shared__ __align__(16) unsigned short Pl[4 * 16 * ATT_P_STRIDE];

    const int tid  = threadIdx.x;
    const int lane = tid & 63;
    const int wave = tid >> 6;
    const int ln15 = lane & 15;
    const int quad = lane >> 4;

    // XCD pinning: id = j*32 + g, g = head-group (b,h), j = q-pair index
    const int g = blockIdx.x & 31;
    const int jj = blockIdx.x >> 5;        // 0..15
    const int h = g & 15;
    const int b = g >> 4;

    const size_t rowbase = (size_t)b * SEQ;
    const size_t hoff    = (size_t)h * HDIM;
    const unsigned short* Kh  = Kb + rowbase * DMODEL + hoff;
    const unsigned short* Vth = Vt + (size_t)(b * NHEADS + h) * HDIM * SEQ;

    const float sc2     = 0.08838834764831845f * 1.4426950408889634f;
    const float slope2  = exp2f(-0.5f * (float)(h + 1)) * 1.4426950408889634f;
    const float slope16 = slope2 * 16.0f;
    const float slope32 = slope2 * 32.0f;

    // staging lane roles
    const int kq  = wave * 8 + (lane >> 4);
    const int ksl = lane & 15;
    const int dq  = wave * 32 + (lane >> 2);
    const int vsl = lane & 3;
    const int vsw = (ln15 >> 1) & 3;

    unsigned short* Pw = &Pl[wave * 16 * ATT_P_STRIDE];

    #pragma unroll 1
    for (int ph = 0; ph < 2; ++ph) {
        const int qblk = ph ? (31 - jj) : jj;
        const int q0w  = qblk * 64 + wave * 16;
        const int nT   = 2 * qblk + 2;

        short8 qf[4];
        {
            const unsigned short* qp =
                Qb + (rowbase + q0w + ln15) * DMODEL + hoff + quad * 8;
            qf[0] = *(const short8*)(qp);
            qf[1] = *(const short8*)(qp + 32);
            qf[2] = *(const short8*)(qp + 64);
            qf[3] = *(const short8*)(qp + 96);
        }

        f32x4 acc[8];
        #pragma unroll
        for (int nt = 0; nt < 8; ++nt) acc[nt] = (f32x4){0.f, 0.f, 0.f, 0.f};
        float lsum[4] = {0.f, 0.f, 0.f, 0.f};

        // incremental ALiBi bias: c0[r] = slope2*(kb+ln15 - (q0w+quad*4+r))
        float c0[4];
        {
            const float base = slope2 * (float)(ln15 - q0w - quad * 4);
            #pragma unroll
            for (int r = 0; r < 4; ++r) c0[r] = base - slope2 * (float)r;
        }

        // ---- stage tile 0 into buffer 0 ----
        #pragma unroll
        for (int i = 0; i < 2; ++i) {
            const int k = kq + i * 4;
            async_load16(Kh + (size_t)k * DMODEL + (ksl ^ (k & 15)) * 8,
                         &Ks[0][(wave * 8 + i * 4) * 128]);
        }
        #pragma unroll
        for (int i = 0; i < 2; ++i) {
            const int d = dq + i * 16;
            async_load16(Vth + (size_t)d * SEQ + (vsl ^ ((d >> 1) & 3)) * 8,
                         &Vs[0][(wave * 32 + i * 16) * 32]);
        }
        __syncthreads();

        for (int t = 0; t < nT; ++t) {
            const int kb  = t * 32;
            const int buf = t & 1;

            if (t + 1 < nT) {
                const int kb1 = kb + 32;
                #pragma unroll
                for (int i = 0; i < 2; ++i) {
                    const int k = kq + i * 4;
                    async_load16(Kh + (size_t)(kb1 + k) * DMODEL + (ksl ^ (k & 15)) * 8,
                                 &Ks[buf ^ 1][(wave * 8 + i * 4) * 128]);
                }
                #pragma unroll
                for (int i = 0; i < 2; ++i) {
                    const int d = dq + i * 16;
                    async_load16(Vth + (size_t)d * SEQ + kb1 + (vsl ^ ((d >> 1) & 3)) * 8,
                                 &Vs[buf ^ 1][(wave * 32 + i * 16) * 32]);
                }
            }

            if (kb <= q0w + 15) {
                const unsigned short* KsB = Ks[buf];
                const unsigned short* VsB = Vs[buf];

                f32x4 s0 = (f32x4){0.f,0.f,0.f,0.f}, s1 = (f32x4){0.f,0.f,0.f,0.f};
                #pragma unroll
                for (int c = 0; c < 4; ++c) {
                    const int slot = (c * 4 + quad) ^ ln15;
                    short8 kf0 = *(const short8*)(&KsB[ln15 * 128 + slot * 8]);
                    short8 kf1 = *(const short8*)(&KsB[(16 + ln15) * 128 + slot * 8]);
                    s0 = __builtin_amdgcn_mfma_f32_16x16x32_bf16(qf[c], kf0, s0, 0, 0, 0);
                    s1 = __builtin_amdgcn_mfma_f32_16x16x32_bf16(qf[c], kf1, s1, 0, 0, 0);
                }

                float p0[4], p1[4];
                if (kb + 31 <= q0w) {
                    // fully unmasked fast path
                    #pragma unroll
                    for (int r = 0; r < 4; ++r) {
                        p0[r] = exp2f(fmaf(s0[r], sc2, c0[r]));
                        p1[r] = exp2f(fmaf(s1[r], sc2, c0[r] + slope16));
                        lsum[r] += p0[r] + p1[r];
                    }
                } else {
                    // diagonal tile: per-element causal mask
                    #pragma unroll
                    for (int r = 0; r < 4; ++r) {
                        const int qrow = q0w + quad * 4 + r;
                        const int k0i = kb + ln15;
                        const float e0 = exp2f(fmaf(s0[r], sc2, c0[r]));
                        const float e1 = exp2f(fmaf(s1[r], sc2, c0[r] + slope16));
                        p0[r] = (k0i      <= qrow) ? e0 : 0.f;
                        p1[r] = (k0i + 16 <= qrow) ? e1 : 0.f;
                        lsum[r] += p0[r] + p1[r];
                    }
                }

                #pragma unroll
                for (int r = 0; r < 4; ++r) {
                    Pw[(quad * 4 + r) * ATT_P_STRIDE + ln15]      = f2bf(p0[r]);
                    Pw[(quad * 4 + r) * ATT_P_STRIDE + 16 + ln15] = f2bf(p1[r]);
                }
                __builtin_amdgcn_s_waitcnt(0xC07F);   // lgkmcnt(0)
                short8 pf = *(const short8*)(&Pw[ln15 * ATT_P_STRIDE + quad * 8]);

                #pragma unroll
                for (int nt = 0; nt < 8; ++nt) {
                    short8 vf = *(const short8*)(
                        &VsB[(nt * 16 + ln15) * 32 + (quad ^ vsw) * 8]);
                    acc[nt] = __builtin_amdgcn_mfma_f32_16x16x32_bf16(pf, vf, acc[nt], 0, 0, 0);
                }
            }

            #pragma unroll
            for (int r = 0; r < 4; ++r) c0[r] += slope32;
            __syncthreads();
        }

        #pragma unroll
        for (int r = 0; r < 4; ++r) {
            float l = lsum[r];
            l += __shfl_xor(l, 1, 64);
            l += __shfl_xor(l, 2, 64);
            l += __shfl_xor(l, 4, 64);
            l += __shfl_xor(l, 8, 64);
            const float inv = 1.0f / l;
            const size_t ob = (rowbase + q0w + quad * 4 + r) * DMODEL + hoff;
            #pragma unroll
            for (int nt = 0; nt < 8; ++nt)
                O[ob + nt * 16 + ln15] = f2bf(acc[nt][r] * inv);
        }
    }
}

// ---------------------------------------------------------------------------
extern "C" void kernel_launch(void* const* d_in, const int* in_sizes, int n_in,
                              void* d_out, int out_size, void* d_ws, size_t ws_size,
                              hipStream_t stream)
{
    const float* x  = (const float*)d_in[0];
    const float* wq = (const float*)d_in[1];
    const float* bq = (const float*)d_in[2];
    const float* wk = (const float*)d_in[3];
    const float* bk = (const float*)d_in[4];
    const float* wv = (const float*)d_in[5];
    const float* bv = (const float*)d_in[6];
    const float* wo = (const float*)d_in[7];
    const float* bo = (const float*)d_in[8];
    float* out = (float*)d_out;

    const size_t bufElems = (size_t)MROWS * DMODEL;   // 8.39M
    unsigned short* Qb  = (unsigned short*)d_ws;
    unsigned short* Kb  = Qb + bufElems;
    unsigned short* Vtg = Kb + bufElems;      // V^T: [B*H][HDIM][SEQ]
    unsigned short* xb  = Vtg + bufElems;     // x bf16; later reused as Ob
    unsigned short* Ob  = xb;                 // alias (xb dead after QKV GEMM)
    unsigned short* Wt  = xb + bufElems;      // 3 slots of 2048*2048 bf16

    const dim3 blk(256);

    convert_bf16_kernel<<<dim3((int)(bufElems / 1024)), blk, 0, stream>>>(
        x, xb, (int)bufElems);

    transpose3_bf16_kernel<<<dim3(32, 32, 3), blk, 0, stream>>>(wq, wk, wv, Wt);

    qkv_gemm_kernel<<<dim3(48, 32), blk, 0, stream>>>(
        xb, Wt, bq, bk, bv, Qb, Kb, Vtg);

    // wo -> Wt slot 0 (QKV GEMM has consumed it by stream order)
    transpose_bf16_kernel<<<dim3(32, 32), blk, 0, stream>>>(wo, Wt, DMODEL, DMODEL);

    attn_kernel<<<dim3(512), blk, 0, stream>>>(Qb, Kb, Vtg, Ob);

    gemm_out_kernel<<<dim3(16, 32), blk, 0, stream>>>(
        Ob, Wt, bo, out, MROWS, DMODEL, DMODEL);
}